// Round 10
// baseline (500.105 us; speedup 1.0000x reference)
//
#include <hip/hip_runtime.h>

typedef __bf16 bf16x8 __attribute__((ext_vector_type(8)));
typedef float floatx4 __attribute__((ext_vector_type(4)));
typedef unsigned short u16;
typedef unsigned int u32;

__device__ __forceinline__ u16 f2bf(float f) {
    union { float f; unsigned int u; } q; q.f = f;
    unsigned int r = q.u + 0x7FFFu + ((q.u >> 16) & 1u);
    return (u16)(r >> 16);
}
__device__ __forceinline__ float bf2f(u16 b) {
    union { unsigned int u; float f; } q; q.u = ((unsigned int)b) << 16;
    return q.f;
}

// async 16B global -> LDS DMA (wave-uniform LDS base + lane*16)
__device__ __forceinline__ void gl2lds16(const u16* g, u16* l) {
    __builtin_amdgcn_global_load_lds((const __attribute__((address_space(1))) u32*)g,
                                     (__attribute__((address_space(3))) u32*)l, 16, 0, 0);
}

// ---------------- fused prep + transposes (one launch) ----------------
// blocks [0,16896): NCHW->NHWC transposes (kin: first 1024, sin: rest);
// blocks [16896,21760): weight packs; [21760]: bn params.
__global__ __launch_bounds__(256) void prep_and_transpose(
    const float* __restrict__ kin, u16* __restrict__ KIN,
    const float* __restrict__ sin_, u16* __restrict__ SIN,
    const float* __restrict__ wk, const float* __restrict__ wsw, const float* __restrict__ wh1,
    const float* __restrict__ gk, const float* __restrict__ bk,
    const float* __restrict__ mk, const float* __restrict__ vk,
    const float* __restrict__ gs, const float* __restrict__ bs,
    const float* __restrict__ ms, const float* __restrict__ vs,
    const float* __restrict__ gh, const float* __restrict__ bh,
    const float* __restrict__ mh, const float* __restrict__ vh,
    u16* __restrict__ WKP, u16* __restrict__ WSP, u16* __restrict__ WH1P,
    float* __restrict__ par)
{
    __shared__ float tile[64][33];
    int bid = blockIdx.x, t = threadIdx.x;
    if (bid < 16896) {
        const float* in; u16* out; int HW, sptiles;
        if (bid < 1024) { in = kin;  out = KIN; HW = 49;  sptiles = 2; }
        else { bid -= 1024; in = sin_; out = SIN; HW = 961; sptiles = 31; }
        int st  = bid % sptiles;
        int tmp = bid / sptiles;
        int ct  = tmp & 3;
        int b   = tmp >> 2;
        int sp0 = st * 32, ci0 = ct * 64;
        int j = t & 31, i8 = t >> 5;
        const float* ip = in + ((size_t)b * 256 + ci0 + i8) * HW + sp0 + j;
#pragma unroll
        for (int k = 0; k < 8; ++k) {
            if (sp0 + j < HW) tile[i8 + k * 8][j] = ip[(size_t)(k * 8) * HW];
        }
        __syncthreads();
        int cl = t & 63, s4 = t >> 6;
#pragma unroll
        for (int k = 0; k < 8; ++k) {
            int spl = s4 + k * 4;
            int sp  = sp0 + spl;
            if (sp < HW) out[((size_t)b * HW + sp) * 256 + ci0 + cl] = f2bf(tile[cl][spl]);
        }
        return;
    }
    bid -= 16896;
    if (bid < 4608) {
        const float* src = (bid < 2304) ? wk : wsw;
        u16* dst = (bid < 2304) ? WKP : WSP;
        int tid = ((bid < 2304) ? bid : bid - 2304) * 256 + t;
        int o  = tid / 2304;
        int k  = tid - o * 2304;
        int rc = k >> 8;
        int ci = k & 255;
        dst[tid] = f2bf(src[o * 2304 + ci * 9 + rc]);
    } else if (bid < 4864) {
        int tid = (bid - 4608) * 256 + t;
        WH1P[tid] = f2bf(wh1[tid]);
    } else {
        float s;
        s = gk[t] * rsqrtf(vk[t] + 1e-5f); par[0*256+t] = s; par[1*256+t] = bk[t] - mk[t]*s;
        s = gs[t] * rsqrtf(vs[t] + 1e-5f); par[2*256+t] = s; par[3*256+t] = bs[t] - ms[t]*s;
        s = gh[t] * rsqrtf(vh[t] + 1e-5f); par[4*256+t] = s; par[5*256+t] = bh[t] - mh[t]*s;
    }
}

// ---------------- conv as implicit GEMM (bf16 MFMA, m97 structure) ----------------
// Used for the 1x1 conv (M=80000, K=256). 128x128 tile, BK=32.
__global__ __launch_bounds__(256) void conv_gemm(
    const u16* __restrict__ Ain, const u16* __restrict__ Wpk,
    const float* __restrict__ scale, const float* __restrict__ shift,
    u16* __restrict__ Out,
    int OHW, int OW, int IW, int bstride, int KW, int nrc, int mblocks)
{
    __shared__ u16 Alds[4096];
    __shared__ u16 Blds[4096];

    const int tot = mblocks * 2;
    const int grp = (tot >> 3) << 3;
    const int lid = blockIdx.x;
    const int nid = (lid < grp) ? ((lid & 7) * (grp >> 3) + (lid >> 3)) : lid;
    const int m0 = (nid >> 1) * 128;
    const int n0 = (nid & 1) * 128;

    const int t    = threadIdx.x;
    const int wave = t >> 6;
    const int lane = t & 63;
    const int quad = lane >> 4;
    const int lrow = lane & 15;

    const int koff = (((t & 3) ^ ((t >> 3) & 3)) << 3);   // elements
    const int r0 = t >> 2;
    int m_a0 = m0 + r0;
    int b0 = m_a0 / OHW; int rem0 = m_a0 - b0 * OHW; int y0 = rem0 / OW; int x0 = rem0 - y0 * OW;
    int m_a1 = m_a0 + 64;
    int b1 = m_a1 / OHW; int rem1 = m_a1 - b1 * OHW; int y1 = rem1 / OW; int x1 = rem1 - y1 * OW;
    const u16* ag0 = Ain + (size_t)b0 * bstride + (size_t)(y0 * IW + x0) * 256 + koff;
    const u16* ag1 = Ain + (size_t)b1 * bstride + (size_t)(y1 * IW + x1) * 256 + koff;
    const int Ktot = nrc * 256;
    const u16* bg0 = Wpk + (size_t)(n0 + r0) * Ktot + koff;
    const u16* bg1 = bg0 + (size_t)64 * Ktot;

    u16* lA0 = Alds + wave * 512;
    u16* lA1 = Alds + 2048 + wave * 512;
    u16* lB0 = Blds + wave * 512;
    u16* lB1 = Blds + 2048 + wave * 512;

    floatx4 zero = {0.f, 0.f, 0.f, 0.f};
    floatx4 acc[4][4];
#pragma unroll
    for (int i = 0; i < 4; ++i)
#pragma unroll
        for (int j = 0; j < 4; ++j) acc[i][j] = zero;

    const int wr  = (wave >> 1) << 6;
    const int wc  = (wave & 1) << 6;
    const int pos = ((quad ^ ((lrow >> 1) & 3)) << 3);

    const int nchunks = nrc << 3;
    for (int ch = 0; ch < nchunks; ++ch) {
        int rc  = ch >> 3;
        int ci0 = (ch & 7) << 5;
        int rr  = rc / KW;
        int cc  = rc - rr * KW;
        int ao  = (rr * IW + cc) * 256 + ci0;
        int bo  = ch << 5;
        __syncthreads();
        gl2lds16(ag0 + ao, lA0);
        gl2lds16(ag1 + ao, lA1);
        gl2lds16(bg0 + bo, lB0);
        gl2lds16(bg1 + bo, lB1);
        __syncthreads();
        bf16x8 af[4], bfr[4];
#pragma unroll
        for (int mi = 0; mi < 4; ++mi)
            af[mi] = *(const bf16x8*)&Alds[(wr + mi * 16 + lrow) * 32 + pos];
#pragma unroll
        for (int ni = 0; ni < 4; ++ni)
            bfr[ni] = *(const bf16x8*)&Blds[(wc + ni * 16 + lrow) * 32 + pos];
#pragma unroll
        for (int mi = 0; mi < 4; ++mi)
#pragma unroll
            for (int ni = 0; ni < 4; ++ni)
                acc[mi][ni] = __builtin_amdgcn_mfma_f32_16x16x32_bf16(af[mi], bfr[ni], acc[mi][ni], 0, 0, 0);
    }

    float sc[4], sh[4];
#pragma unroll
    for (int ni = 0; ni < 4; ++ni) {
        int gn = n0 + wc + ni * 16 + lrow;
        sc[ni] = scale[gn];
        sh[ni] = shift[gn];
    }
#pragma unroll
    for (int mi = 0; mi < 4; ++mi) {
        int gm = m0 + wr + mi * 16 + (quad << 2);
#pragma unroll
        for (int ri = 0; ri < 4; ++ri) {
            size_t ro = (size_t)(gm + ri) * 256 + n0 + wc + lrow;
#pragma unroll
            for (int ni = 0; ni < 4; ++ni) {
                float v = acc[mi][ni][ri] * sc[ni] + sh[ni];
                v = fmaxf(v, 0.f);
                Out[ro + ni * 16] = f2bf(v);
            }
        }
    }
}

// ---------------- fused 256x128 conv GEMM, barrier-free body, 2 blocks/CU ----------------
// R9 post-mortem: 256x256 tile => acc=128 regs/thread => 1 block/CU => boundary
// vmcnt(0)+barrier stalls the whole CU (43% of compute floor). This version:
// BM=256 x BN=128, 512 thr (8 waves 4m x 2n, per-wave 64x64, acc[4][4]=64 regs),
// BK=32, LDS 48KB (A[2][256][32] + B[2][128][32]) => with launch_bounds(512,4)
// 2 blocks/CU co-resident: one block's drain hides under the other's MFMA (m97
// mechanism, m114). Barrier-free K-tile body (R9-proven); one vmcnt(0)+barrier
// per tile. Swizzle for 4-slot rows: stored slot s of row r holds k-chunk
// (s ^ (r&3) ^ ((r>>2)&3)) -- 2-way-free per 16-lane phase (3-term needed at
// BK=32; the 2-term degenerates to 4-way).
// Blocks [0,842): search (421 mblocks x 2 n-halves, n-half fastest => both
// halves share an XCD L2 for the A re-read). [842,868): kernel branch.
#define NS_BLK 842
__global__ __launch_bounds__(512, 4) void conv_gemm256(
    const u16* __restrict__ AinS, const u16* __restrict__ WpkS,
    const float* __restrict__ parS, u16* __restrict__ OutS,
    const u16* __restrict__ AinK, const u16* __restrict__ WpkK,
    const float* __restrict__ parK, u16* __restrict__ OutK)
{
    __shared__ __align__(16) u16 Alds[2][256][32];
    __shared__ __align__(16) u16 Blds[2][128][32];

    const int Ktot = 2304;
    const int NKT  = 72;

    const int lid = blockIdx.x;
    const bool isk = (lid >= NS_BLK);

    // bijective XCD-contiguous remap over 842 (q=105, r=2)
    int nid;
    if (!isk) {
        const int xcd = lid & 7, sub = lid >> 3;
        nid = (xcd < 2) ? (xcd * 106 + sub) : (212 + (xcd - 2) * 105 + sub);
    } else {
        nid = lid - NS_BLK;
    }
    const int m0 = (nid >> 1) << 8;
    const int n0 = (nid & 1) << 7;

    const int OHW     = isk ? 25    : 841;
    const int OW      = isk ? 5     : 29;
    const int IW      = isk ? 7     : 31;
    const int bstride = isk ? 12544 : 246016;
    const int Mtot    = isk ? 3200  : 107648;
    const u16* Ain    = isk ? AinK : AinS;
    const u16* Wpk    = isk ? WpkK : WpkS;
    const float* scale = isk ? parK : parS;
    const float* shift = scale + 256;
    u16* Out          = isk ? OutK : OutS;

    const int t     = threadIdx.x;
    const int wave  = t >> 6;
    const int lane  = t & 63;
    const int lrow  = lane & 15;
    const int lquad = lane >> 4;
    const int wmBase = (wave >> 1) << 6;   // 0,64,128,192
    const int wnBase = (wave & 1) << 6;    // 0,64

    // staging sources: A 2 slots/thread (1024 slots), B 1 slot/thread (512 slots)
    const u16* pA[2];
#pragma unroll
    for (int j = 0; j < 2; ++j) {
        int u = j * 512 + t;
        int row = u >> 2, slot = u & 3;
        int ko = ((slot ^ (row & 3) ^ ((row >> 2) & 3)) << 3);   // pre-swizzled k elems
        int m = m0 + row; if (m >= Mtot) m = Mtot - 1;
        int b = m / OHW; int rem = m - b * OHW; int y = rem / OW; int x = rem - y * OW;
        pA[j] = Ain + (size_t)b * bstride + (size_t)(y * IW + x) * 256 + ko;
    }
    const u16* pB;
    {
        int row = t >> 2, slot = t & 3;
        int ko = ((slot ^ (row & 3) ^ ((row >> 2) & 3)) << 3);
        pB = Wpk + (size_t)(n0 + row) * Ktot + ko;
    }

    // swizzled ds_read offset (u16 units)
    const int xo = ((lquad ^ (lrow & 3) ^ ((lrow >> 2) & 3)) << 3);

    floatx4 acc[4][4];
#pragma unroll
    for (int i = 0; i < 4; ++i)
#pragma unroll
        for (int j = 0; j < 4; ++j) acc[i][j] = (floatx4){0.f, 0.f, 0.f, 0.f};

    // prologue: stage K-tile 0 into buf 0
    gl2lds16(pA[0], &Alds[0][0][0] + 0 * 4096 + wave * 512);
    gl2lds16(pA[1], &Alds[0][0][0] + 1 * 4096 + wave * 512);
    gl2lds16(pB,    &Blds[0][0][0] + wave * 512);
    asm volatile("s_waitcnt vmcnt(0)" ::: "memory");
    __builtin_amdgcn_s_barrier();

#pragma unroll 2
    for (int kt = 0; kt < NKT; ++kt) {
        const int c = kt & 1;
        const u16* Ab = &Alds[c][0][0];
        const u16* Bb = &Blds[c][0][0];
        u16* An = &Alds[c ^ 1][0][0];
        u16* Bn = &Blds[c ^ 1][0][0];
        const int pf = (kt + 1 < NKT);
        const int kt1 = kt + 1;
        const int rc = kt1 >> 3;
        const int rr = rc / 3;
        const int cc = rc - rr * 3;
        const int aoff = (rr * IW + cc) * 256 + ((kt1 & 7) << 5);
        const int boff = kt1 << 5;

        // issue next-tile DMAs up front (land before this tile's boundary drain
        // of the OTHER block overlaps; 2-block TLP hides the residue)
        if (pf) {
            gl2lds16(pA[0] + aoff, An + 0 * 4096 + wave * 512);
            gl2lds16(pA[1] + aoff, An + 1 * 4096 + wave * 512);
            gl2lds16(pB + boff,    Bn + wave * 512);
        }

        // barrier-free compute: compiler pipelines ds_reads under MFMA
        bf16x8 bB[4], aF[4];
#pragma unroll
        for (int ni = 0; ni < 4; ++ni)
            bB[ni] = *(const bf16x8*)(Bb + (wnBase + ni * 16 + lrow) * 32 + xo);
#pragma unroll
        for (int mi = 0; mi < 4; ++mi)
            aF[mi] = *(const bf16x8*)(Ab + (wmBase + mi * 16 + lrow) * 32 + xo);
#pragma unroll
        for (int mi = 0; mi < 4; ++mi)
#pragma unroll
            for (int ni = 0; ni < 4; ++ni)
                acc[mi][ni] = __builtin_amdgcn_mfma_f32_16x16x32_bf16(aF[mi], bB[ni], acc[mi][ni], 0, 0, 0);

        // boundary: drain DMAs, resync waves
        asm volatile("s_waitcnt vmcnt(0)" ::: "memory");
        __builtin_amdgcn_s_barrier();
    }

    // epilogue: bn + relu + bf16 store
    float sc[4], sh[4];
#pragma unroll
    for (int ni = 0; ni < 4; ++ni) {
        int gn = n0 + wnBase + ni * 16 + lrow;
        sc[ni] = scale[gn];
        sh[ni] = shift[gn];
    }
#pragma unroll
    for (int mi = 0; mi < 4; ++mi) {
        int gm0 = m0 + wmBase + mi * 16 + (lquad << 2);
#pragma unroll
        for (int ri = 0; ri < 4; ++ri) {
            int gm = gm0 + ri;
            if (gm < Mtot) {
                size_t ro = (size_t)gm * 256 + n0 + wnBase + lrow;
#pragma unroll
                for (int ni = 0; ni < 4; ++ni) {
                    float v = acc[mi][ni][ri] * sc[ni] + sh[ni];
                    v = fmaxf(v, 0.f);
                    Out[ro + ni * 16] = f2bf(v);
                }
            }
        }
    }
}

// ---------------- depthwise xcorr (vectorized bf16x8 loads, XCD-clustered) ----------------
__global__ __launch_bounds__(256) void xcorr(const u16* __restrict__ ss, const u16* __restrict__ kk,
                                             u16* __restrict__ f) {
    int lid = blockIdx.x;
    int bid = (lid & 7) * 400 + (lid >> 3);   // b*25 + y, XCD-contiguous (3200%8==0)
    int b = bid / 25, y = bid - b * 25;
    int t = threadIdx.x;
    int cg = (t & 31) << 3;         // channel base
    int xg = t >> 5;                // 0..7
    const u16* kbase = kk + (size_t)b * 25 * 256 + cg;
    const u16* sbase = ss + (size_t)(b * 29 + y) * 29 * 256 + cg;

    float acc[4][8];
#pragma unroll
    for (int j = 0; j < 4; ++j)
#pragma unroll
        for (int e = 0; e < 8; ++e) acc[j][e] = 0.f;

#pragma unroll
    for (int r = 0; r < 5; ++r) {
        const u16* srow = sbase + (size_t)r * 29 * 256;
#pragma unroll
        for (int c = 0; c < 5; ++c) {
            bf16x8 kv = *(const bf16x8*)(kbase + (r * 5 + c) * 256);
            float kf[8];
#pragma unroll
            for (int e = 0; e < 8; ++e) kf[e] = (float)kv[e];
#pragma unroll
            for (int j = 0; j < 4; ++j) {
                int x = xg + 8 * j;
                if (x < 25) {
                    bf16x8 sv = *(const bf16x8*)(srow + (size_t)(x + c) * 256);
#pragma unroll
                    for (int e = 0; e < 8; ++e) acc[j][e] += (float)sv[e] * kf[e];
                }
            }
        }
    }

    u16* fb = f + (size_t)(b * 25 + y) * 25 * 256 + cg;
#pragma unroll
    for (int j = 0; j < 4; ++j) {
        int x = xg + 8 * j;
        if (x < 25) {
            u16 pk[8];
#pragma unroll
            for (int e = 0; e < 8; ++e) pk[e] = f2bf(acc[j][e]);
            *(bf16x8*)(fb + (size_t)x * 256) = *(const bf16x8*)pk;
        }
    }
}

// ---------------- final 1x1 conv (256->20) + bias, NCHW fp32 out ----------------
__global__ __launch_bounds__(256) void head(const u16* __restrict__ h, const float* __restrict__ w2,
                                            const float* __restrict__ b2, float* __restrict__ out) {
    __shared__ __align__(16) u16   hl[25 * 264];
    __shared__ __align__(16) float wl[20 * 260];
    int bid = blockIdx.x;            // b*25 + y
    int b = bid / 25, y = bid - b * 25;
    int t = threadIdx.x;
    const u16* hrow = h + (size_t)(b * 25 + y) * 25 * 256;
    for (int i = t; i < 800; i += 256) {
        int x = i >> 5, c8 = i & 31;
        *(bf16x8*)&hl[x * 264 + c8 * 8] = *(const bf16x8*)&hrow[i * 8];
    }
    for (int i = t; i < 1280; i += 256) {
        int co = i >> 6, c4 = i & 63;
        *(float4*)&wl[co * 260 + c4 * 4] = *(const float4*)&w2[(size_t)co * 256 + c4 * 4];
    }
    __syncthreads();
    for (int o = t; o < 500; o += 256) {
        int x = o / 20, co = o - x * 20;
        float acc = b2[co];
        const u16* hp = &hl[x * 264];
        const float* wp = &wl[co * 260];
#pragma unroll 4
        for (int k = 0; k < 256; k += 8) {
            bf16x8 hv = *(const bf16x8*)(hp + k);
            float4 w0 = *(const float4*)(wp + k);
            float4 w1v = *(const float4*)(wp + k + 4);
            acc += (float)hv[0] * w0.x + (float)hv[1] * w0.y
                 + (float)hv[2] * w0.z + (float)hv[3] * w0.w
                 + (float)hv[4] * w1v.x + (float)hv[5] * w1v.y
                 + (float)hv[6] * w1v.z + (float)hv[7] * w1v.w;
        }
        out[(size_t)((b * 20 + co) * 25 + y) * 25 + x] = acc;
    }
}

// ---------------- workspace layout ----------------
#define OFF_SIN  0ull
#define SZ_SIN   62980096ull      // 128*31*31*256*2
#define OFF_KIN  (OFF_SIN + SZ_SIN)
#define SZ_KIN   3211264ull       // 128*7*7*256*2
#define OFF_WKP  (OFF_KIN + SZ_KIN)
#define SZ_WKP   1179648ull
#define OFF_WSP  (OFF_WKP + SZ_WKP)
#define SZ_WSP   1179648ull
#define OFF_WH1P (OFF_WSP + SZ_WSP)
#define SZ_WH1P  131072ull
#define OFF_PAR  (OFF_WH1P + SZ_WH1P)
#define SZ_PAR   8192ull
#define OFF_KK   (OFF_PAR + SZ_PAR)
#define SZ_KK    1638400ull       // 128*25*256*2
#define OFF_SS   (OFF_KK + SZ_KK)
#define SZ_SS    55115776ull      // 128*29*29*256*2
#define OFF_F    OFF_SIN          // reuse: SIN dead after conv
#define OFF_H    OFF_SS           // reuse: SS dead after xcorr

extern "C" void kernel_launch(void* const* d_in, const int* in_sizes, int n_in,
                              void* d_out, int out_size, void* d_ws, size_t ws_size,
                              hipStream_t stream) {
    const float* kin  = (const float*)d_in[0];
    const float* sin_ = (const float*)d_in[1];
    const float* wk   = (const float*)d_in[2];
    const float* gk   = (const float*)d_in[3];
    const float* bk   = (const float*)d_in[4];
    const float* mk   = (const float*)d_in[5];
    const float* vk   = (const float*)d_in[6];
    const float* wsw  = (const float*)d_in[7];
    const float* gs   = (const float*)d_in[8];
    const float* bs   = (const float*)d_in[9];
    const float* ms   = (const float*)d_in[10];
    const float* vs   = (const float*)d_in[11];
    const float* wh1  = (const float*)d_in[12];
    const float* gh   = (const float*)d_in[13];
    const float* bh   = (const float*)d_in[14];
    const float* mh   = (const float*)d_in[15];
    const float* vh   = (const float*)d_in[16];
    const float* wh2  = (const float*)d_in[17];
    const float* bh2  = (const float*)d_in[18];
    float* out = (float*)d_out;

    char* w = (char*)d_ws;
    u16*   SIN  = (u16*)(w + OFF_SIN);
    u16*   KIN  = (u16*)(w + OFF_KIN);
    u16*   WKP  = (u16*)(w + OFF_WKP);
    u16*   WSP  = (u16*)(w + OFF_WSP);
    u16*   WH1P = (u16*)(w + OFF_WH1P);
    float* PAR  = (float*)(w + OFF_PAR);
    u16*   KK   = (u16*)(w + OFF_KK);
    u16*   SS   = (u16*)(w + OFF_SS);
    u16*   F    = (u16*)(w + OFF_F);
    u16*   H    = (u16*)(w + OFF_H);

    // fused prep + transposes (one launch)
    prep_and_transpose<<<21761, 256, 0, stream>>>(kin, KIN, sin_, SIN,
                                                  wk, wsw, wh1,
                                                  gk, bk, mk, vk, gs, bs, ms, vs, gh, bh, mh, vh,
                                                  WKP, WSP, WH1P, PAR);

    // fused search conv (blocks 0..841, 421 mblocks x 2 n-halves)
    // + kernel-branch conv (blocks 842..867)
    conv_gemm256<<<868, 512, 0, stream>>>(SIN, WSP, PAR + 512, SS,
                                          KIN, WKP, PAR + 0, KK);
    // depthwise xcorr (standalone, zero LDS, full occupancy)
    xcorr<<<3200, 256, 0, stream>>>(SS, KK, F);
    // 1x1 conv + bn + relu: M=80000 (625 m-blocks), dedicated GEMM
    conv_gemm<<<1250, 256, 0, stream>>>(F, WH1P, PAR + 1024, PAR + 1280, H,
                                        625, 25, 25, 160000, 1, 1, 625);
    // head
    head<<<3200, 256, 0, stream>>>(H, wh2, bh2, out);

    (void)in_sizes; (void)n_in; (void)out_size; (void)ws_size;
}

// Round 11
// 461.542 us; speedup vs baseline: 1.0836x; 1.0836x over previous
//
#include <hip/hip_runtime.h>

typedef __bf16 bf16x8 __attribute__((ext_vector_type(8)));
typedef float floatx4 __attribute__((ext_vector_type(4)));
typedef unsigned short u16;
typedef unsigned int u32;

__device__ __forceinline__ u16 f2bf(float f) {
    union { float f; unsigned int u; } q; q.f = f;
    unsigned int r = q.u + 0x7FFFu + ((q.u >> 16) & 1u);
    return (u16)(r >> 16);
}
__device__ __forceinline__ float bf2f(u16 b) {
    union { unsigned int u; float f; } q; q.u = ((unsigned int)b) << 16;
    return q.f;
}

// async 16B global -> LDS DMA (wave-uniform LDS base + lane*16)
__device__ __forceinline__ void gl2lds16(const u16* g, u16* l) {
    __builtin_amdgcn_global_load_lds((const __attribute__((address_space(1))) u32*)g,
                                     (__attribute__((address_space(3))) u32*)l, 16, 0, 0);
}

// ---------------- fused prep + transposes (one launch) ----------------
__global__ __launch_bounds__(256) void prep_and_transpose(
    const float* __restrict__ kin, u16* __restrict__ KIN,
    const float* __restrict__ sin_, u16* __restrict__ SIN,
    const float* __restrict__ wk, const float* __restrict__ wsw, const float* __restrict__ wh1,
    const float* __restrict__ gk, const float* __restrict__ bk,
    const float* __restrict__ mk, const float* __restrict__ vk,
    const float* __restrict__ gs, const float* __restrict__ bs,
    const float* __restrict__ ms, const float* __restrict__ vs,
    const float* __restrict__ gh, const float* __restrict__ bh,
    const float* __restrict__ mh, const float* __restrict__ vh,
    u16* __restrict__ WKP, u16* __restrict__ WSP, u16* __restrict__ WH1P,
    float* __restrict__ par)
{
    __shared__ float tile[64][33];
    int bid = blockIdx.x, t = threadIdx.x;
    if (bid < 16896) {
        const float* in; u16* out; int HW, sptiles;
        if (bid < 1024) { in = kin;  out = KIN; HW = 49;  sptiles = 2; }
        else { bid -= 1024; in = sin_; out = SIN; HW = 961; sptiles = 31; }
        int st  = bid % sptiles;
        int tmp = bid / sptiles;
        int ct  = tmp & 3;
        int b   = tmp >> 2;
        int sp0 = st * 32, ci0 = ct * 64;
        int j = t & 31, i8 = t >> 5;
        const float* ip = in + ((size_t)b * 256 + ci0 + i8) * HW + sp0 + j;
#pragma unroll
        for (int k = 0; k < 8; ++k) {
            if (sp0 + j < HW) tile[i8 + k * 8][j] = ip[(size_t)(k * 8) * HW];
        }
        __syncthreads();
        int cl = t & 63, s4 = t >> 6;
#pragma unroll
        for (int k = 0; k < 8; ++k) {
            int spl = s4 + k * 4;
            int sp  = sp0 + spl;
            if (sp < HW) out[((size_t)b * HW + sp) * 256 + ci0 + cl] = f2bf(tile[cl][spl]);
        }
        return;
    }
    bid -= 16896;
    if (bid < 4608) {
        const float* src = (bid < 2304) ? wk : wsw;
        u16* dst = (bid < 2304) ? WKP : WSP;
        int tid = ((bid < 2304) ? bid : bid - 2304) * 256 + t;
        int o  = tid / 2304;
        int k  = tid - o * 2304;
        int rc = k >> 8;
        int ci = k & 255;
        dst[tid] = f2bf(src[o * 2304 + ci * 9 + rc]);
    } else if (bid < 4864) {
        int tid = (bid - 4608) * 256 + t;
        WH1P[tid] = f2bf(wh1[tid]);
    } else {
        float s;
        s = gk[t] * rsqrtf(vk[t] + 1e-5f); par[0*256+t] = s; par[1*256+t] = bk[t] - mk[t]*s;
        s = gs[t] * rsqrtf(vs[t] + 1e-5f); par[2*256+t] = s; par[3*256+t] = bs[t] - ms[t]*s;
        s = gh[t] * rsqrtf(vh[t] + 1e-5f); par[4*256+t] = s; par[5*256+t] = bh[t] - mh[t]*s;
    }
}

// ---------------- conv as implicit GEMM (bf16 MFMA, m97 structure) ----------------
// Used for the 1x1 conv (M=80000, K=256). 128x128 tile, BK=32.
__global__ __launch_bounds__(256) void conv_gemm(
    const u16* __restrict__ Ain, const u16* __restrict__ Wpk,
    const float* __restrict__ scale, const float* __restrict__ shift,
    u16* __restrict__ Out,
    int OHW, int OW, int IW, int bstride, int KW, int nrc, int mblocks)
{
    __shared__ u16 Alds[4096];
    __shared__ u16 Blds[4096];

    const int tot = mblocks * 2;
    const int grp = (tot >> 3) << 3;
    const int lid = blockIdx.x;
    const int nid = (lid < grp) ? ((lid & 7) * (grp >> 3) + (lid >> 3)) : lid;
    const int m0 = (nid >> 1) * 128;
    const int n0 = (nid & 1) * 128;

    const int t    = threadIdx.x;
    const int wave = t >> 6;
    const int lane = t & 63;
    const int quad = lane >> 4;
    const int lrow = lane & 15;

    const int koff = (((t & 3) ^ ((t >> 3) & 3)) << 3);   // elements
    const int r0 = t >> 2;
    int m_a0 = m0 + r0;
    int b0 = m_a0 / OHW; int rem0 = m_a0 - b0 * OHW; int y0 = rem0 / OW; int x0 = rem0 - y0 * OW;
    int m_a1 = m_a0 + 64;
    int b1 = m_a1 / OHW; int rem1 = m_a1 - b1 * OHW; int y1 = rem1 / OW; int x1 = rem1 - y1 * OW;
    const u16* ag0 = Ain + (size_t)b0 * bstride + (size_t)(y0 * IW + x0) * 256 + koff;
    const u16* ag1 = Ain + (size_t)b1 * bstride + (size_t)(y1 * IW + x1) * 256 + koff;
    const int Ktot = nrc * 256;
    const u16* bg0 = Wpk + (size_t)(n0 + r0) * Ktot + koff;
    const u16* bg1 = bg0 + (size_t)64 * Ktot;

    u16* lA0 = Alds + wave * 512;
    u16* lA1 = Alds + 2048 + wave * 512;
    u16* lB0 = Blds + wave * 512;
    u16* lB1 = Blds + 2048 + wave * 512;

    floatx4 zero = {0.f, 0.f, 0.f, 0.f};
    floatx4 acc[4][4];
#pragma unroll
    for (int i = 0; i < 4; ++i)
#pragma unroll
        for (int j = 0; j < 4; ++j) acc[i][j] = zero;

    const int wr  = (wave >> 1) << 6;
    const int wc  = (wave & 1) << 6;
    const int pos = ((quad ^ ((lrow >> 1) & 3)) << 3);

    const int nchunks = nrc << 3;
    for (int ch = 0; ch < nchunks; ++ch) {
        int rc  = ch >> 3;
        int ci0 = (ch & 7) << 5;
        int rr  = rc / KW;
        int cc  = rc - rr * KW;
        int ao  = (rr * IW + cc) * 256 + ci0;
        int bo  = ch << 5;
        __syncthreads();
        gl2lds16(ag0 + ao, lA0);
        gl2lds16(ag1 + ao, lA1);
        gl2lds16(bg0 + bo, lB0);
        gl2lds16(bg1 + bo, lB1);
        __syncthreads();
        bf16x8 af[4], bfr[4];
#pragma unroll
        for (int mi = 0; mi < 4; ++mi)
            af[mi] = *(const bf16x8*)&Alds[(wr + mi * 16 + lrow) * 32 + pos];
#pragma unroll
        for (int ni = 0; ni < 4; ++ni)
            bfr[ni] = *(const bf16x8*)&Blds[(wc + ni * 16 + lrow) * 32 + pos];
#pragma unroll
        for (int mi = 0; mi < 4; ++mi)
#pragma unroll
            for (int ni = 0; ni < 4; ++ni)
                acc[mi][ni] = __builtin_amdgcn_mfma_f32_16x16x32_bf16(af[mi], bfr[ni], acc[mi][ni], 0, 0, 0);
    }

    float sc[4], sh[4];
#pragma unroll
    for (int ni = 0; ni < 4; ++ni) {
        int gn = n0 + wc + ni * 16 + lrow;
        sc[ni] = scale[gn];
        sh[ni] = shift[gn];
    }
#pragma unroll
    for (int mi = 0; mi < 4; ++mi) {
        int gm = m0 + wr + mi * 16 + (quad << 2);
#pragma unroll
        for (int ri = 0; ri < 4; ++ri) {
            size_t ro = (size_t)(gm + ri) * 256 + n0 + wc + lrow;
#pragma unroll
            for (int ni = 0; ni < 4; ++ni) {
                float v = acc[mi][ni][ri] * sc[ni] + sh[ni];
                v = fmaxf(v, 0.f);
                Out[ro + ni * 16] = f2bf(v);
            }
        }
    }
}

// ---------------- fused 256x256 conv GEMM, barrier-free K-tile body (R9, proven 143.5us) ----------------
// Zero intra-tile barriers; one vmcnt(0)+barrier per K-tile; compiler pipelines
// ds_reads under MFMA. BK=64 swizzle (0 bank conflicts measured): stored slot s
// of row r holds k-chunk (s ^ (r&7)); read slot lquad^(lrow&7); k-half 1 = ^4.
// R10 lesson: BK=32 reshape for 2 blocks/CU regressed (3-term swizzle -> 1.6e7
// bank conflicts, +20MB FETCH, halved arith intensity). This tile shape is final.
#define NS_BLK 421
__global__ __launch_bounds__(512, 2) void conv_gemm256(
    const u16* __restrict__ AinS, const u16* __restrict__ WpkS,
    const float* __restrict__ parS, u16* __restrict__ OutS,
    const u16* __restrict__ AinK, const u16* __restrict__ WpkK,
    const float* __restrict__ parK, u16* __restrict__ OutK)
{
    __shared__ __align__(16) u16 Alds[2][256][64];
    __shared__ __align__(16) u16 Blds[2][256][64];

    const int Ktot = 2304;
    const int NKT  = 36;
    const int KW   = 3;

    const int lid = blockIdx.x;
    const bool isk = (lid >= NS_BLK);

    int nid;
    if (!isk) {
        const int xcd = lid & 7, sub = lid >> 3;
        nid = (xcd < 5) ? (xcd * 53 + sub) : (265 + (xcd - 5) * 52 + sub);
    } else {
        nid = lid - NS_BLK;
    }
    const int m0 = nid << 8;

    const int OHW     = isk ? 25    : 841;
    const int OW      = isk ? 5     : 29;
    const int IW      = isk ? 7     : 31;
    const int bstride = isk ? 12544 : 246016;
    const int Mtot    = isk ? 3200  : 107648;
    const u16* Ain    = isk ? AinK : AinS;
    const u16* Wpk    = isk ? WpkK : WpkS;
    const float* scale = isk ? parK : parS;
    const float* shift = scale + 256;
    u16* Out          = isk ? OutK : OutS;

    const int t     = threadIdx.x;
    const int wave  = t >> 6;
    const int lane  = t & 63;
    const int lrow  = lane & 15;
    const int lquad = lane >> 4;
    const int wmBase = (wave >> 2) << 7;   // 0 or 128
    const int wnBase = (wave & 3) << 6;    // 0..192

    const u16* pA[4];
    const u16* pB[4];
#pragma unroll
    for (int j = 0; j < 4; ++j) {
        int u = j * 512 + t;
        int row = u >> 3, slot = u & 7;
        int ko = ((slot ^ (row & 7)) << 3);          // pre-swizzled k elems (0..56)
        int m = m0 + row; if (m >= Mtot) m = Mtot - 1;
        int b = m / OHW; int rem = m - b * OHW; int y = rem / OW; int x = rem - y * OW;
        pA[j] = Ain + (size_t)b * bstride + (size_t)(y * IW + x) * 256 + ko;
        pB[j] = Wpk + (size_t)row * (size_t)Ktot + ko;
    }

    const int xo0 = ((lquad ^ (lrow & 7)) << 3);
    const int xo1 = xo0 ^ 32;

    floatx4 acc[8][4];
#pragma unroll
    for (int i = 0; i < 8; ++i)
#pragma unroll
        for (int j = 0; j < 4; ++j) acc[i][j] = (floatx4){0.f, 0.f, 0.f, 0.f};

#pragma unroll
    for (int j = 0; j < 4; ++j)
        gl2lds16(pA[j], &Alds[0][0][0] + j * 4096 + wave * 512);
#pragma unroll
    for (int j = 0; j < 4; ++j)
        gl2lds16(pB[j], &Blds[0][0][0] + j * 4096 + wave * 512);
    asm volatile("s_waitcnt vmcnt(0)" ::: "memory");
    __builtin_amdgcn_s_barrier();

#define LOADA(mb) do {                                              \
        const u16* _p = Ab + (wmBase + (mb) * 16 + lrow) * 64;      \
        aF[0][0] = *(const bf16x8*)(_p + xo0);                      \
        aF[0][1] = *(const bf16x8*)(_p + xo1);                      \
        aF[1][0] = *(const bf16x8*)(_p + 1024 + xo0);               \
        aF[1][1] = *(const bf16x8*)(_p + 1024 + xo1);               \
    } while (0)

#define MFMA16(mb) do {                                                                               \
        _Pragma("unroll")                                                                             \
        for (int _n = 0; _n < 4; ++_n) {                                                              \
            acc[(mb)][_n]     = __builtin_amdgcn_mfma_f32_16x16x32_bf16(aF[0][0], bB[_n][0], acc[(mb)][_n], 0, 0, 0);     \
            acc[(mb)][_n]     = __builtin_amdgcn_mfma_f32_16x16x32_bf16(aF[0][1], bB[_n][1], acc[(mb)][_n], 0, 0, 0);     \
            acc[(mb) + 1][_n] = __builtin_amdgcn_mfma_f32_16x16x32_bf16(aF[1][0], bB[_n][0], acc[(mb) + 1][_n], 0, 0, 0); \
            acc[(mb) + 1][_n] = __builtin_amdgcn_mfma_f32_16x16x32_bf16(aF[1][1], bB[_n][1], acc[(mb) + 1][_n], 0, 0, 0); \
        }                                                                                             \
    } while (0)

#pragma unroll 2
    for (int kt = 0; kt < NKT; ++kt) {
        const int c = kt & 1;
        const u16* Ab = &Alds[c][0][0];
        const u16* Bb = &Blds[c][0][0];
        u16* An = &Alds[c ^ 1][0][0];
        u16* Bn = &Blds[c ^ 1][0][0];
        const int pf = (kt + 1 < NKT);
        const int kt1 = kt + 1;
        const int rc = kt1 >> 2;
        const int rr = rc / KW;
        const int cc = rc - rr * KW;
        const int aoffA = (rr * IW + cc) * 256 + ((kt1 & 3) << 6);
        const int boffB = kt1 << 6;

        if (pf) {
#pragma unroll
            for (int j = 0; j < 4; ++j)
                gl2lds16(pA[j] + aoffA, An + j * 4096 + wave * 512);
#pragma unroll
            for (int j = 0; j < 4; ++j)
                gl2lds16(pB[j] + boffB, Bn + j * 4096 + wave * 512);
        }

        bf16x8 bB[4][2];
        bf16x8 aF[2][2];
#pragma unroll
        for (int ni = 0; ni < 4; ++ni) {
            const u16* _p = Bb + (wnBase + ni * 16 + lrow) * 64;
            bB[ni][0] = *(const bf16x8*)(_p + xo0);
            bB[ni][1] = *(const bf16x8*)(_p + xo1);
        }
        LOADA(0);
        MFMA16(0);
        LOADA(2);
        MFMA16(2);
        LOADA(4);
        MFMA16(4);
        LOADA(6);
        MFMA16(6);

        asm volatile("s_waitcnt vmcnt(0)" ::: "memory");
        __builtin_amdgcn_s_barrier();
    }

#undef LOADA
#undef MFMA16

    float sc[4], sh[4];
#pragma unroll
    for (int ni = 0; ni < 4; ++ni) {
        int gn = wnBase + ni * 16 + lrow;
        sc[ni] = scale[gn];
        sh[ni] = shift[gn];
    }
#pragma unroll
    for (int mi = 0; mi < 8; ++mi) {
        int gm0 = m0 + wmBase + mi * 16 + (lquad << 2);
#pragma unroll
        for (int ri = 0; ri < 4; ++ri) {
            int gm = gm0 + ri;
            if (gm < Mtot) {
                size_t ro = (size_t)gm * 256 + wnBase + lrow;
#pragma unroll
                for (int ni = 0; ni < 4; ++ni) {
                    float v = acc[mi][ni][ri] * sc[ni] + sh[ni];
                    v = fmaxf(v, 0.f);
                    Out[ro + ni * 16] = f2bf(v);
                }
            }
        }
    }
}

// ---------------- depthwise xcorr: LDS row staging (cuts L1/L2 traffic 5x) ----------------
// R10 accounting: per-thread tap loads = 125 x 16B x 256thr = 500KB/block of
// cache traffic for 74KB unique S data (1.6GB total, L2-per-XCD oversubscribed
// -> L3 latency). Fix: stage each S row ONCE in LDS (14.8KB), taps read LDS.
// Reads: lanes 0-31 read contiguous 512B per (x+c) -> conflict-free.
// S global traffic: 74KB/block (was ~400KB); K unchanged (L2-hot).
__global__ __launch_bounds__(256) void xcorr(const u16* __restrict__ ss, const u16* __restrict__ kk,
                                             u16* __restrict__ f) {
    __shared__ __align__(16) u16 Srow[29 * 256];   // 14.8 KB -> 8 blocks/CU

    int lid = blockIdx.x;
    int bid = (lid & 7) * 400 + (lid >> 3);   // b*25 + y, XCD-contiguous (3200%8==0)
    int b = bid / 25, y = bid - b * 25;
    int t = threadIdx.x;
    int cg = (t & 31) << 3;         // channel base
    int xg = t >> 5;                // 0..7
    const u16* kbase = kk + (size_t)b * 25 * 256 + cg;
    const u16* sbase = ss + (size_t)(b * 29 + y) * 29 * 256;

    float acc[4][8];
#pragma unroll
    for (int j = 0; j < 4; ++j)
#pragma unroll
        for (int e = 0; e < 8; ++e) acc[j][e] = 0.f;

#pragma unroll
    for (int r = 0; r < 5; ++r) {
        // stage row y+r (29*256 u16 = 928 x bf16x8)
        __syncthreads();   // prior taps done reading Srow
        const u16* grow = sbase + (size_t)r * 29 * 256;
        for (int i = t; i < 928; i += 256)
            *(bf16x8*)&Srow[i * 8] = *(const bf16x8*)&grow[i * 8];
        __syncthreads();
#pragma unroll
        for (int c = 0; c < 5; ++c) {
            bf16x8 kv = *(const bf16x8*)(kbase + (r * 5 + c) * 256);
            float kf[8];
#pragma unroll
            for (int e = 0; e < 8; ++e) kf[e] = (float)kv[e];
#pragma unroll
            for (int j = 0; j < 4; ++j) {
                int x = xg + 8 * j;
                if (x < 25) {
                    bf16x8 sv = *(const bf16x8*)&Srow[(x + c) * 256 + cg];
#pragma unroll
                    for (int e = 0; e < 8; ++e) acc[j][e] += (float)sv[e] * kf[e];
                }
            }
        }
    }

    u16* fb = f + (size_t)(b * 25 + y) * 25 * 256 + cg;
#pragma unroll
    for (int j = 0; j < 4; ++j) {
        int x = xg + 8 * j;
        if (x < 25) {
            u16 pk[8];
#pragma unroll
            for (int e = 0; e < 8; ++e) pk[e] = f2bf(acc[j][e]);
            *(bf16x8*)(fb + (size_t)x * 256) = *(const bf16x8*)pk;
        }
    }
}

// ---------------- final 1x1 conv (256->20) + bias, NCHW fp32 out ----------------
__global__ __launch_bounds__(256) void head(const u16* __restrict__ h, const float* __restrict__ w2,
                                            const float* __restrict__ b2, float* __restrict__ out) {
    __shared__ __align__(16) u16   hl[25 * 264];
    __shared__ __align__(16) float wl[20 * 260];
    int bid = blockIdx.x;            // b*25 + y
    int b = bid / 25, y = bid - b * 25;
    int t = threadIdx.x;
    const u16* hrow = h + (size_t)(b * 25 + y) * 25 * 256;
    for (int i = t; i < 800; i += 256) {
        int x = i >> 5, c8 = i & 31;
        *(bf16x8*)&hl[x * 264 + c8 * 8] = *(const bf16x8*)&hrow[i * 8];
    }
    for (int i = t; i < 1280; i += 256) {
        int co = i >> 6, c4 = i & 63;
        *(float4*)&wl[co * 260 + c4 * 4] = *(const float4*)&w2[(size_t)co * 256 + c4 * 4];
    }
    __syncthreads();
    for (int o = t; o < 500; o += 256) {
        int x = o / 20, co = o - x * 20;
        float acc = b2[co];
        const u16* hp = &hl[x * 264];
        const float* wp = &wl[co * 260];
#pragma unroll 4
        for (int k = 0; k < 256; k += 8) {
            bf16x8 hv = *(const bf16x8*)(hp + k);
            float4 w0 = *(const float4*)(wp + k);
            float4 w1v = *(const float4*)(wp + k + 4);
            acc += (float)hv[0] * w0.x + (float)hv[1] * w0.y
                 + (float)hv[2] * w0.z + (float)hv[3] * w0.w
                 + (float)hv[4] * w1v.x + (float)hv[5] * w1v.y
                 + (float)hv[6] * w1v.z + (float)hv[7] * w1v.w;
        }
        out[(size_t)((b * 20 + co) * 25 + y) * 25 + x] = acc;
    }
}

// ---------------- workspace layout ----------------
#define OFF_SIN  0ull
#define SZ_SIN   62980096ull      // 128*31*31*256*2
#define OFF_KIN  (OFF_SIN + SZ_SIN)
#define SZ_KIN   3211264ull       // 128*7*7*256*2
#define OFF_WKP  (OFF_KIN + SZ_KIN)
#define SZ_WKP   1179648ull
#define OFF_WSP  (OFF_WKP + SZ_WKP)
#define SZ_WSP   1179648ull
#define OFF_WH1P (OFF_WSP + SZ_WSP)
#define SZ_WH1P  131072ull
#define OFF_PAR  (OFF_WH1P + SZ_WH1P)
#define SZ_PAR   8192ull
#define OFF_KK   (OFF_PAR + SZ_PAR)
#define SZ_KK    1638400ull       // 128*25*256*2
#define OFF_SS   (OFF_KK + SZ_KK)
#define SZ_SS    55115776ull      // 128*29*29*256*2
#define OFF_F    OFF_SIN          // reuse: SIN dead after conv
#define OFF_H    OFF_SS           // reuse: SS dead after xcorr

extern "C" void kernel_launch(void* const* d_in, const int* in_sizes, int n_in,
                              void* d_out, int out_size, void* d_ws, size_t ws_size,
                              hipStream_t stream) {
    const float* kin  = (const float*)d_in[0];
    const float* sin_ = (const float*)d_in[1];
    const float* wk   = (const float*)d_in[2];
    const float* gk   = (const float*)d_in[3];
    const float* bk   = (const float*)d_in[4];
    const float* mk   = (const float*)d_in[5];
    const float* vk   = (const float*)d_in[6];
    const float* wsw  = (const float*)d_in[7];
    const float* gs   = (const float*)d_in[8];
    const float* bs   = (const float*)d_in[9];
    const float* ms   = (const float*)d_in[10];
    const float* vs   = (const float*)d_in[11];
    const float* wh1  = (const float*)d_in[12];
    const float* gh   = (const float*)d_in[13];
    const float* bh   = (const float*)d_in[14];
    const float* mh   = (const float*)d_in[15];
    const float* vh   = (const float*)d_in[16];
    const float* wh2  = (const float*)d_in[17];
    const float* bh2  = (const float*)d_in[18];
    float* out = (float*)d_out;

    char* w = (char*)d_ws;
    u16*   SIN  = (u16*)(w + OFF_SIN);
    u16*   KIN  = (u16*)(w + OFF_KIN);
    u16*   WKP  = (u16*)(w + OFF_WKP);
    u16*   WSP  = (u16*)(w + OFF_WSP);
    u16*   WH1P = (u16*)(w + OFF_WH1P);
    float* PAR  = (float*)(w + OFF_PAR);
    u16*   KK   = (u16*)(w + OFF_KK);
    u16*   SS   = (u16*)(w + OFF_SS);
    u16*   F    = (u16*)(w + OFF_F);
    u16*   H    = (u16*)(w + OFF_H);

    // fused prep + transposes (one launch)
    prep_and_transpose<<<21761, 256, 0, stream>>>(kin, KIN, sin_, SIN,
                                                  wk, wsw, wh1,
                                                  gk, bk, mk, vk, gs, bs, ms, vs, gh, bh, mh, vh,
                                                  WKP, WSP, WH1P, PAR);

    // fused search conv (blocks 0..420) + kernel-branch conv (blocks 421..433)
    conv_gemm256<<<434, 512, 0, stream>>>(SIN, WSP, PAR + 512, SS,
                                          KIN, WKP, PAR + 0, KK);
    // depthwise xcorr (LDS row staging)
    xcorr<<<3200, 256, 0, stream>>>(SS, KK, F);
    // 1x1 conv + bn + relu: M=80000 (625 m-blocks), dedicated GEMM
    conv_gemm<<<1250, 256, 0, stream>>>(F, WH1P, PAR + 1024, PAR + 1280, H,
                                        625, 25, 25, 160000, 1, 1, 625);
    // head
    head<<<3200, 256, 0, stream>>>(H, wh2, bh2, out);

    (void)in_sizes; (void)n_in; (void)out_size; (void)ws_size;
}